// Round 2
// baseline (4136.176 us; speedup 1.0000x reference)
//
#include <hip/hip_runtime.h>
#include <math.h>

#define DD 512
#define SS 1024
#define BB 2
#define HH 8
#define LL 8
#define FF 2048
#define VV 32000
#define ROWS 2048            // B*S
#define NTOT 65536000u       // B*S*V
#define NCHUNK 16
#define CLEN 64              // SS / NCHUNK

// ---------------------------------------------------------------- embedding
__global__ __launch_bounds__(256) void embed_kernel(
    const int* __restrict__ ids, const float* __restrict__ emb,
    const float* __restrict__ pos, float* __restrict__ x)
{
    unsigned idx = blockIdx.x * 256u + threadIdx.x;        // ROWS*DD
    unsigned row = idx >> 9, d = idx & 511u;
    unsigned s = row & (SS - 1);
    x[idx] = emb[(size_t)ids[row] * DD + d] + pos[(size_t)s * DD + d];
}

// ---------------------------------------------------------------- rope tables
__global__ __launch_bounds__(256) void rope_table_kernel(float* __restrict__ ctab,
                                                         float* __restrict__ stab)
{
    unsigned idx = blockIdx.x * 256u + threadIdx.x;        // SS*32
    unsigned j = idx & 31u, s = idx >> 5;
    float invf = (float)(1.0 / pow(10000.0, (double)(2 * j) / 64.0));
    float f = (float)s * invf;                              // fp32 mult, like np
    ctab[idx] = (float)cos((double)f);
    stab[idx] = (float)sin((double)f);
}

__device__ __forceinline__ float elu1(float x) {
    return x > 0.f ? x + 1.f : expm1f(x) + 1.f;
}

// ---------------------------------------------------------------- chunked linear attention
// rope+elu(+mask) folded in: kernels read RAW q/k from the qkv gemm.
// Stage A: per-(b,h,chunk) partial state  S_c[d][e] = sum_{s in c} k[s][d]*v[s][e]
//          and z_c[d] = sum_{s in c} k[s][d].   grid = B*H*NCHUNK = 256 blocks.
__global__ __launch_bounds__(256) void chunk_state_kernel(
    const float* __restrict__ k, const float* __restrict__ v,
    const float* __restrict__ ctab, const float* __restrict__ stab,
    const float* __restrict__ mask,
    float* __restrict__ st, float* __restrict__ zs)
{
    int blk = blockIdx.x;                 // bh*16 + c
    int bh = blk >> 4, c = blk & 15;
    int b = bh >> 3, h = bh & 7;
    int t = threadIdx.x;
    int e = t & 63, dg = t >> 6, d0 = dg << 4;
    size_t base = (size_t)b * SS * DD + (size_t)h * 64 + (size_t)(c * CLEN) * DD;
    __shared__ float kk[64][64], vv[64][64];
#pragma unroll
    for (int i = 0; i < 4; ++i) {
        int idx = t + i * 256;
        int r = idx >> 4, c4 = (idx & 15) << 2;
        size_t go = base + (size_t)r * DD + c4;
        *(float4*)&kk[r][c4] = *(const float4*)(k + go);
        *(float4*)&vv[r][c4] = *(const float4*)(v + go);
    }
    __syncthreads();
    // rope + elu1 + mask on kk in place (pairs j, j+32)
#pragma unroll
    for (int i = 0; i < 8; ++i) {
        int idx = t + (i << 8);           // 0..2047
        int r = idx >> 5, j = idx & 31;
        int s = c * CLEN + r;
        float cc = ctab[s * 32 + j], sn = stab[s * 32 + j];
        float m = mask[b * SS + s];
        float k1 = kk[r][j], k2 = kk[r][j + 32];
        kk[r][j]      = elu1(k1 * cc - k2 * sn) * m;
        kk[r][j + 32] = elu1(k2 * cc + k1 * sn) * m;
    }
    __syncthreads();
    float acc[16];
#pragma unroll
    for (int j = 0; j < 16; ++j) acc[j] = 0.f;
    float z = 0.f;
    for (int s = 0; s < CLEN; ++s) {
        float vval = vv[s][e];
        float kr16[16];
        *(float4*)&kr16[0]  = *(const float4*)&kk[s][d0];
        *(float4*)&kr16[4]  = *(const float4*)&kk[s][d0 + 4];
        *(float4*)&kr16[8]  = *(const float4*)&kk[s][d0 + 8];
        *(float4*)&kr16[12] = *(const float4*)&kk[s][d0 + 12];
#pragma unroll
        for (int j = 0; j < 16; ++j) acc[j] += kr16[j] * vval;
        if (t < 64) z += kk[s][t];
    }
    size_t so = (size_t)blk * 4096;
#pragma unroll
    for (int j = 0; j < 16; ++j)
        st[so + (size_t)(d0 + j) * 64 + e] = acc[j];
    if (t < 64) zs[(size_t)blk * 64 + t] = z;
}

// Stage B: in-place EXCLUSIVE prefix over the 16 chunks per (b,h). grid = 16.
__global__ __launch_bounds__(256) void chunk_prefix_kernel(
    float* __restrict__ st, float* __restrict__ zs)
{
    int bh = blockIdx.x;
    int t = threadIdx.x;
    float run[16];
#pragma unroll
    for (int i = 0; i < 16; ++i) run[i] = 0.f;
    float zrun = 0.f;
    for (int c = 0; c < NCHUNK; ++c) {
        size_t so = ((size_t)bh * NCHUNK + c) * 4096;
#pragma unroll
        for (int i = 0; i < 16; ++i) {
            size_t o = so + t + i * 256;
            float tmp = st[o];
            st[o] = run[i];
            run[i] += tmp;
        }
        if (t < 64) {
            size_t zo = ((size_t)bh * NCHUNK + c) * 64 + t;
            float tz = zs[zo];
            zs[zo] = zrun;
            zrun += tz;
        }
    }
}

// Stage C: per-chunk 64-step scan seeded from the exclusive prefix state.
__global__ __launch_bounds__(256) void chunk_scan_kernel(
    const float* __restrict__ q, const float* __restrict__ k,
    const float* __restrict__ v, float* __restrict__ a,
    const float* __restrict__ ctab, const float* __restrict__ stab,
    const float* __restrict__ mask,
    const float* __restrict__ st, const float* __restrict__ zs)
{
    int blk = blockIdx.x;
    int bh = blk >> 4, c = blk & 15;
    int b = bh >> 3, h = bh & 7;
    int t = threadIdx.x;
    int e = t & 63, dg = t >> 6, d0 = dg << 4;
    size_t base = (size_t)b * SS * DD + (size_t)h * 64 + (size_t)(c * CLEN) * DD;
    __shared__ float kk[64][64], vv[64][64], qq[64][64];
    __shared__ float pnum[4][64];
    __shared__ float den_sh;
#pragma unroll
    for (int i = 0; i < 4; ++i) {
        int idx = t + i * 256;
        int r = idx >> 4, c4 = (idx & 15) << 2;
        size_t go = base + (size_t)r * DD + c4;
        *(float4*)&kk[r][c4] = *(const float4*)(k + go);
        *(float4*)&vv[r][c4] = *(const float4*)(v + go);
        *(float4*)&qq[r][c4] = *(const float4*)(q + go);
    }
    __syncthreads();
    // rope + elu1 on qq (no mask) and kk (mask), pairs (j, j+32)
#pragma unroll
    for (int i = 0; i < 8; ++i) {
        int idx = t + (i << 8);
        int r = idx >> 5, j = idx & 31;
        int s = c * CLEN + r;
        float cc = ctab[s * 32 + j], sn = stab[s * 32 + j];
        float m = mask[b * SS + s];
        float k1 = kk[r][j], k2 = kk[r][j + 32];
        kk[r][j]      = elu1(k1 * cc - k2 * sn) * m;
        kk[r][j + 32] = elu1(k2 * cc + k1 * sn) * m;
        float q1 = qq[r][j], q2 = qq[r][j + 32];
        qq[r][j]      = elu1(q1 * cc - q2 * sn);
        qq[r][j + 32] = elu1(q2 * cc + q1 * sn);
    }
    float Sacc[16];
    size_t so = (size_t)blk * 4096;
#pragma unroll
    for (int j = 0; j < 16; ++j)
        Sacc[j] = st[so + (size_t)(d0 + j) * 64 + e];
    float zreg = 0.f;
    if (t < 64) zreg = zs[(size_t)blk * 64 + t];
    __syncthreads();
    for (int s = 0; s < CLEN; ++s) {
        float vval = vv[s][e];
        float kr16[16], qr16[16];
        *(float4*)&kr16[0]  = *(const float4*)&kk[s][d0];
        *(float4*)&kr16[4]  = *(const float4*)&kk[s][d0 + 4];
        *(float4*)&kr16[8]  = *(const float4*)&kk[s][d0 + 8];
        *(float4*)&kr16[12] = *(const float4*)&kk[s][d0 + 12];
        *(float4*)&qr16[0]  = *(const float4*)&qq[s][d0];
        *(float4*)&qr16[4]  = *(const float4*)&qq[s][d0 + 4];
        *(float4*)&qr16[8]  = *(const float4*)&qq[s][d0 + 8];
        *(float4*)&qr16[12] = *(const float4*)&qq[s][d0 + 12];
        float p = 0.f;
#pragma unroll
        for (int j = 0; j < 16; ++j) {
            Sacc[j] += kr16[j] * vval;     // S[d][e] += k[d]*v[e]
            p += qr16[j] * Sacc[j];        // num[e] partial
        }
        pnum[dg][e] = p;
        if (t < 64) {
            zreg += kk[s][t];
            float pd = qq[s][t] * zreg;
#pragma unroll
            for (int o = 32; o; o >>= 1) pd += __shfl_down(pd, o);
            if (t == 0) den_sh = pd + 1e-6f;
        }
        __syncthreads();
        if (t < 64) {
            float num = ((pnum[0][t] + pnum[1][t]) + pnum[2][t]) + pnum[3][t];
            a[base + (size_t)s * DD + t] = num / den_sh;
        }
        __syncthreads();
    }
}

// ---------------------------------------------------------------- generic SGEMM (dbuf)
// C[M,N] = A[M,K] @ B[K,N] + bias (+ res) (+ gelu). 64x64 tile, K-tile 16.
// Double-buffered LDS: ONE barrier per k-tile, next tile's loads issued early.
__global__ __launch_bounds__(256) void gemm_kernel(
    const float* __restrict__ A, const float* __restrict__ B,
    const float* __restrict__ bias, const float* __restrict__ res,
    float* __restrict__ C, int M, int N, int K, int act)
{
    __shared__ float As[2][16][68];
    __shared__ float Bs[2][16][68];
    const int t = threadIdx.x;
    const int bn = blockIdx.x, bm = blockIdx.y;
    const int m0 = bm * 64, n0 = bn * 64;
    const int tx = t & 15, ty = t >> 4;
    const int ar = t >> 2, ac = (t & 3) << 2;
    const int br = t >> 4, bc = (t & 15) << 2;
    const float* Ap = A + (size_t)(m0 + ar) * K + ac;
    const float* Bp = B + (size_t)br * N + (n0 + bc);
    float4 av = *(const float4*)(Ap);
    float4 bv = *(const float4*)(Bp);
    As[0][ac + 0][ar] = av.x; As[0][ac + 1][ar] = av.y;
    As[0][ac + 2][ar] = av.z; As[0][ac + 3][ar] = av.w;
    *(float4*)&Bs[0][br][bc] = bv;
    __syncthreads();
    float acc[4][4] = {};
    const int nt = K >> 4;
    for (int it = 0; it < nt; ++it) {
        const int cur = it & 1;
        const bool more = (it + 1) < nt;
        float4 av2, bv2;
        if (more) {
            av2 = *(const float4*)(Ap + ((it + 1) << 4));
            bv2 = *(const float4*)(Bp + (size_t)((it + 1) << 4) * N);
        }
#pragma unroll
        for (int kkk = 0; kkk < 16; ++kkk) {
            float4 a4 = *(const float4*)&As[cur][kkk][ty << 2];
            float4 b4 = *(const float4*)&Bs[cur][kkk][tx << 2];
            float aa[4] = {a4.x, a4.y, a4.z, a4.w};
            float bb4[4] = {b4.x, b4.y, b4.z, b4.w};
#pragma unroll
            for (int i = 0; i < 4; ++i)
#pragma unroll
                for (int jj = 0; jj < 4; ++jj)
                    acc[i][jj] += aa[i] * bb4[jj];
        }
        if (more) {
            As[cur ^ 1][ac + 0][ar] = av2.x; As[cur ^ 1][ac + 1][ar] = av2.y;
            As[cur ^ 1][ac + 2][ar] = av2.z; As[cur ^ 1][ac + 3][ar] = av2.w;
            *(float4*)&Bs[cur ^ 1][br][bc] = bv2;
            __syncthreads();
        }
    }
#pragma unroll
    for (int i = 0; i < 4; ++i) {
        int m = m0 + (ty << 2) + i;
        size_t rowoff = (size_t)m * N + n0 + (tx << 2);
        float tmp[4];
#pragma unroll
        for (int jj = 0; jj < 4; ++jj) {
            int n = n0 + (tx << 2) + jj;
            float vv = acc[i][jj] + bias[n];
            if (res) vv += res[rowoff + jj];
            if (act == 1) {
                float x3 = vv * vv * vv;
                vv = vv * (0.5f * (1.0f + tanhf(0.7978845608028654f * (vv + 0.044715f * x3))));
            }
            tmp[jj] = vv;
        }
        float4 o4 = {tmp[0], tmp[1], tmp[2], tmp[3]};
        *(float4*)(C + rowoff) = o4;
    }
}

// ---------------------------------------------------------------- fused QKV GEMM (dbuf)
// grid (24, 32): bn>>3 selects {q,k,v}. M=2048, N=512, K=512.
__global__ __launch_bounds__(256) void qkv_kernel(
    const float* __restrict__ A,
    const float* __restrict__ Wq, const float* __restrict__ Wk, const float* __restrict__ Wv,
    const float* __restrict__ bq, const float* __restrict__ bk, const float* __restrict__ bv,
    float* __restrict__ Qo, float* __restrict__ Ko, float* __restrict__ Vo)
{
    __shared__ float As[2][16][68];
    __shared__ float Bs[2][16][68];
    const int t = threadIdx.x;
    const int bn = blockIdx.x, bm = blockIdx.y;
    const int sel = bn >> 3;
    const float* B    = sel == 0 ? Wq : (sel == 1 ? Wk : Wv);
    const float* bias = sel == 0 ? bq : (sel == 1 ? bk : bv);
    float*       C    = sel == 0 ? Qo : (sel == 1 ? Ko : Vo);
    const int m0 = bm * 64, n0 = (bn & 7) << 6;
    const int tx = t & 15, ty = t >> 4;
    const int ar = t >> 2, ac = (t & 3) << 2;
    const int br = t >> 4, bc = (t & 15) << 2;
    const float* Ap = A + (size_t)(m0 + ar) * DD + ac;
    const float* Bp = B + (size_t)br * DD + (n0 + bc);
    float4 av = *(const float4*)(Ap);
    float4 bv4 = *(const float4*)(Bp);
    As[0][ac + 0][ar] = av.x; As[0][ac + 1][ar] = av.y;
    As[0][ac + 2][ar] = av.z; As[0][ac + 3][ar] = av.w;
    *(float4*)&Bs[0][br][bc] = bv4;
    __syncthreads();
    float acc[4][4] = {};
    const int nt = DD >> 4;   // 32
    for (int it = 0; it < nt; ++it) {
        const int cur = it & 1;
        const bool more = (it + 1) < nt;
        float4 av2, bv2;
        if (more) {
            av2 = *(const float4*)(Ap + ((it + 1) << 4));
            bv2 = *(const float4*)(Bp + (size_t)((it + 1) << 4) * DD);
        }
#pragma unroll
        for (int kkk = 0; kkk < 16; ++kkk) {
            float4 a4 = *(const float4*)&As[cur][kkk][ty << 2];
            float4 b4 = *(const float4*)&Bs[cur][kkk][tx << 2];
            float aa[4] = {a4.x, a4.y, a4.z, a4.w};
            float bb4[4] = {b4.x, b4.y, b4.z, b4.w};
#pragma unroll
            for (int i = 0; i < 4; ++i)
#pragma unroll
                for (int jj = 0; jj < 4; ++jj)
                    acc[i][jj] += aa[i] * bb4[jj];
        }
        if (more) {
            As[cur ^ 1][ac + 0][ar] = av2.x; As[cur ^ 1][ac + 1][ar] = av2.y;
            As[cur ^ 1][ac + 2][ar] = av2.z; As[cur ^ 1][ac + 3][ar] = av2.w;
            *(float4*)&Bs[cur ^ 1][br][bc] = bv2;
            __syncthreads();
        }
    }
#pragma unroll
    for (int i = 0; i < 4; ++i) {
        int m = m0 + (ty << 2) + i;
        size_t rowoff = (size_t)m * DD + n0 + (tx << 2);
        float4 o4;
        o4.x = acc[i][0] + bias[n0 + (tx << 2) + 0];
        o4.y = acc[i][1] + bias[n0 + (tx << 2) + 1];
        o4.z = acc[i][2] + bias[n0 + (tx << 2) + 2];
        o4.w = acc[i][3] + bias[n0 + (tx << 2) + 3];
        *(float4*)(C + rowoff) = o4;
    }
}

// ---------------------------------------------------------------- split-K SGEMM (dbuf)
// blockIdx.z = ks (0/1). Partial ks covers K-range [ks*K/2, (ks+1)*K/2).
// Raw partial (no bias/res/act) written to C + ks*M*N. Reduction fused in ln_fuse.
__global__ __launch_bounds__(256) void gemm_splitk_kernel(
    const float* __restrict__ A, const float* __restrict__ B,
    float* __restrict__ C, int M, int N, int K)
{
    __shared__ float As[2][16][68];
    __shared__ float Bs[2][16][68];
    const int t = threadIdx.x;
    const int bn = blockIdx.x, bm = blockIdx.y, ks = blockIdx.z;
    const int Kc = K >> 1;
    const int m0 = bm * 64, n0 = bn * 64;
    const int tx = t & 15, ty = t >> 4;
    const int ar = t >> 2, ac = (t & 3) << 2;
    const int br = t >> 4, bc = (t & 15) << 2;
    const float* Ap = A + (size_t)(m0 + ar) * K + ks * Kc + ac;
    const float* Bp = B + (size_t)(ks * Kc + br) * N + (n0 + bc);
    float4 av = *(const float4*)(Ap);
    float4 bv = *(const float4*)(Bp);
    As[0][ac + 0][ar] = av.x; As[0][ac + 1][ar] = av.y;
    As[0][ac + 2][ar] = av.z; As[0][ac + 3][ar] = av.w;
    *(float4*)&Bs[0][br][bc] = bv;
    __syncthreads();
    float acc[4][4] = {};
    const int nt = Kc >> 4;
    for (int it = 0; it < nt; ++it) {
        const int cur = it & 1;
        const bool more = (it + 1) < nt;
        float4 av2, bv2;
        if (more) {
            av2 = *(const float4*)(Ap + ((it + 1) << 4));
            bv2 = *(const float4*)(Bp + (size_t)((it + 1) << 4) * N);
        }
#pragma unroll
        for (int kkk = 0; kkk < 16; ++kkk) {
            float4 a4 = *(const float4*)&As[cur][kkk][ty << 2];
            float4 b4 = *(const float4*)&Bs[cur][kkk][tx << 2];
            float aa[4] = {a4.x, a4.y, a4.z, a4.w};
            float bb4[4] = {b4.x, b4.y, b4.z, b4.w};
#pragma unroll
            for (int i = 0; i < 4; ++i)
#pragma unroll
                for (int jj = 0; jj < 4; ++jj)
                    acc[i][jj] += aa[i] * bb4[jj];
        }
        if (more) {
            As[cur ^ 1][ac + 0][ar] = av2.x; As[cur ^ 1][ac + 1][ar] = av2.y;
            As[cur ^ 1][ac + 2][ar] = av2.z; As[cur ^ 1][ac + 3][ar] = av2.w;
            *(float4*)&Bs[cur ^ 1][br][bc] = bv2;
            __syncthreads();
        }
    }
    float* Cp = C + (size_t)ks * M * N;
#pragma unroll
    for (int i = 0; i < 4; ++i) {
        int m = m0 + (ty << 2) + i;
        size_t rowoff = (size_t)m * N + n0 + (tx << 2);
        float4 o4 = {acc[i][0], acc[i][1], acc[i][2], acc[i][3]};
        *(float4*)(Cp + rowoff) = o4;
    }
}

// ---------------------------------------------------------------- big SGEMM (dbuf + XCD swizzle)
// 128x128 tile, 8x8 micro-tile. For Wout (N=32000).
#define PAD128 132
__global__ __launch_bounds__(256) void gemm128_kernel(
    const float* __restrict__ A, const float* __restrict__ B,
    const float* __restrict__ bias, const float* __restrict__ res,
    float* __restrict__ C, int M, int N, int K, int act)
{
    __shared__ float As[2][16][PAD128];   // transposed A-tile: As[k][m]
    __shared__ float Bs[2][16][PAD128];
    const int t = threadIdx.x;
    // XCD-aware swizzle: each XCD gets a contiguous virt range, bm-fastest so the
    // full A panel (4 MB) stays resident in its L2 while B streams exactly once.
    unsigned p = blockIdx.y * gridDim.x + blockIdx.x;
    unsigned total = gridDim.x * gridDim.y;
    unsigned bn, bm;
    if ((total & 7u) == 0u) {
        unsigned per = total >> 3;
        unsigned virt = (p & 7u) * per + (p >> 3);
        bm = virt % gridDim.y;
        bn = virt / gridDim.y;
    } else { bn = blockIdx.x; bm = blockIdx.y; }
    const int m0 = bm * 128, n0 = bn * 128;
    const int tx = t & 15, ty = t >> 4;
    const int ar = t >> 2, ac = (t & 3) << 2;     // A stage: 64 rows x 16 cols, 2 halves
    const int br = t >> 5, bc = (t & 31) << 2;    // B stage: 8 rows x 128 cols, 2 halves
    const float* Ap0 = A + (size_t)(m0 + ar) * K + ac;
    const float* Ap1 = A + (size_t)(m0 + 64 + ar) * K + ac;
    const float* Bp0 = B + (size_t)br * N + (n0 + bc);
    const float* Bp1 = B + (size_t)(br + 8) * N + (n0 + bc);
    float4 a0 = *(const float4*)(Ap0);
    float4 a1 = *(const float4*)(Ap1);
    float4 b0 = *(const float4*)(Bp0);
    float4 b1 = *(const float4*)(Bp1);
    As[0][ac + 0][ar] = a0.x; As[0][ac + 1][ar] = a0.y;
    As[0][ac + 2][ar] = a0.z; As[0][ac + 3][ar] = a0.w;
    As[0][ac + 0][64 + ar] = a1.x; As[0][ac + 1][64 + ar] = a1.y;
    As[0][ac + 2][64 + ar] = a1.z; As[0][ac + 3][64 + ar] = a1.w;
    *(float4*)&Bs[0][br][bc] = b0;
    *(float4*)&Bs[0][br + 8][bc] = b1;
    __syncthreads();
    float acc[8][8] = {};
    const int nt = K >> 4;
    for (int it = 0; it < nt; ++it) {
        const int cur = it & 1;
        const bool more = (it + 1) < nt;
        float4 a0n, a1n, b0n, b1n;
        if (more) {
            int ko = (it + 1) << 4;
            a0n = *(const float4*)(Ap0 + ko);
            a1n = *(const float4*)(Ap1 + ko);
            b0n = *(const float4*)(Bp0 + (size_t)ko * N);
            b1n = *(const float4*)(Bp1 + (size_t)ko * N);
        }
#pragma unroll
        for (int kkk = 0; kkk < 16; ++kkk) {
            float4 aA = *(const float4*)&As[cur][kkk][ty << 2];
            float4 aB = *(const float4*)&As[cur][kkk][64 + (ty << 2)];
            float4 bA = *(const float4*)&Bs[cur][kkk][tx << 2];
            float4 bB = *(const float4*)&Bs[cur][kkk][64 + (tx << 2)];
            float am[8] = {aA.x, aA.y, aA.z, aA.w, aB.x, aB.y, aB.z, aB.w};
            float bn8[8] = {bA.x, bA.y, bA.z, bA.w, bB.x, bB.y, bB.z, bB.w};
#pragma unroll
            for (int i = 0; i < 8; ++i)
#pragma unroll
                for (int jj = 0; jj < 8; ++jj)
                    acc[i][jj] += am[i] * bn8[jj];
        }
        if (more) {
            As[cur ^ 1][ac + 0][ar] = a0n.x; As[cur ^ 1][ac + 1][ar] = a0n.y;
            As[cur ^ 1][ac + 2][ar] = a0n.z; As[cur ^ 1][ac + 3][ar] = a0n.w;
            As[cur ^ 1][ac + 0][64 + ar] = a1n.x; As[cur ^ 1][ac + 1][64 + ar] = a1n.y;
            As[cur ^ 1][ac + 2][64 + ar] = a1n.z; As[cur ^ 1][ac + 3][64 + ar] = a1n.w;
            *(float4*)&Bs[cur ^ 1][br][bc] = b0n;
            *(float4*)&Bs[cur ^ 1][br + 8][bc] = b1n;
            __syncthreads();
        }
    }
#pragma unroll
    for (int i = 0; i < 8; ++i) {
        int m = m0 + ((i >> 2) << 6) + (ty << 2) + (i & 3);
#pragma unroll
        for (int nh = 0; nh < 2; ++nh) {
            int nb = n0 + (nh << 6) + (tx << 2);
            size_t off = (size_t)m * N + nb;
            float tmp[4];
#pragma unroll
            for (int jj = 0; jj < 4; ++jj) {
                float vv2 = acc[i][(nh << 2) + jj] + bias[nb + jj];
                if (res) vv2 += res[off + jj];
                if (act == 1) {
                    float x3 = vv2 * vv2 * vv2;
                    vv2 = vv2 * (0.5f * (1.0f + tanhf(0.7978845608028654f * (vv2 + 0.044715f * x3))));
                }
                tmp[jj] = vv2;
            }
            float4 o4 = {tmp[0], tmp[1], tmp[2], tmp[3]};
            *(float4*)(C + off) = o4;
        }
    }
}

// ---------------------------------------------------------------- cond layernorm (plain)
__global__ __launch_bounds__(256) void ln_kernel(
    const float* __restrict__ in, float* __restrict__ out,
    const float* __restrict__ g, const float* __restrict__ b,
    const int* __restrict__ cond)
{
    int row = blockIdx.x;
    int c = cond[row >> 10];
    const float* xr = in + (size_t)row * DD;
    int t = threadIdx.x;
    float v0 = xr[t], v1 = xr[t + 256];
    __shared__ float sm[8];
    int lane = t & 63, w = t >> 6;
    float s1 = v0 + v1;
#pragma unroll
    for (int o = 32; o; o >>= 1) s1 += __shfl_down(s1, o);
    if (lane == 0) sm[w] = s1;
    __syncthreads();
    if (t == 0) sm[0] = sm[0] + sm[1] + sm[2] + sm[3];
    __syncthreads();
    float mu = sm[0] * (1.0f / 512.0f);
    __syncthreads();
    float d0 = v0 - mu, d1 = v1 - mu;
    float s2 = d0 * d0 + d1 * d1;
#pragma unroll
    for (int o = 32; o; o >>= 1) s2 += __shfl_down(s2, o);
    if (lane == 0) sm[w] = s2;
    __syncthreads();
    if (t == 0) sm[0] = sm[0] + sm[1] + sm[2] + sm[3];
    __syncthreads();
    float var = sm[0] * (1.0f / 512.0f);
    float sd = sqrtf(var + 1e-5f);
    const float* gr = g + (size_t)c * DD;
    const float* br = b + (size_t)c * DD;
    out[(size_t)row * DD + t]       = (d0 / sd) * gr[t] + br[t];
    out[(size_t)row * DD + t + 256] = (d1 / sd) * gr[t + 256] + br[t + 256];
}

// ---------------------------------------------------------------- fused splitk-reduce + residual + cond LN
// val = p0 + p1 + bias[d] + x (residual); LN(val) -> x (in place).
__global__ __launch_bounds__(256) void ln_fuse_kernel(
    const float* __restrict__ p0, const float* __restrict__ p1,
    const float* __restrict__ bias, float* __restrict__ x,
    const float* __restrict__ g, const float* __restrict__ b,
    const int* __restrict__ cond)
{
    int row = blockIdx.x;
    int c = cond[row >> 10];
    int t = threadIdx.x;
    size_t o0 = (size_t)row * DD + t, o1 = o0 + 256;
    float v0 = p0[o0] + p1[o0] + bias[t]       + x[o0];
    float v1 = p0[o1] + p1[o1] + bias[t + 256] + x[o1];
    __shared__ float sm[8];
    int lane = t & 63, w = t >> 6;
    float s1 = v0 + v1;
#pragma unroll
    for (int o = 32; o; o >>= 1) s1 += __shfl_down(s1, o);
    if (lane == 0) sm[w] = s1;
    __syncthreads();
    if (t == 0) sm[0] = sm[0] + sm[1] + sm[2] + sm[3];
    __syncthreads();
    float mu = sm[0] * (1.0f / 512.0f);
    __syncthreads();
    float d0 = v0 - mu, d1 = v1 - mu;
    float s2 = d0 * d0 + d1 * d1;
#pragma unroll
    for (int o = 32; o; o >>= 1) s2 += __shfl_down(s2, o);
    if (lane == 0) sm[w] = s2;
    __syncthreads();
    if (t == 0) sm[0] = sm[0] + sm[1] + sm[2] + sm[3];
    __syncthreads();
    float var = sm[0] * (1.0f / 512.0f);
    float sd = sqrtf(var + 1e-5f);
    const float* gr = g + (size_t)c * DD;
    const float* br = b + (size_t)c * DD;
    x[o0] = (d0 / sd) * gr[t]       + br[t];
    x[o1] = (d1 / sd) * gr[t + 256] + br[t + 256];
}

// ---------------------------------------------------------------- threefry gumbel
__device__ __forceinline__ unsigned rotl32(unsigned x, int r) {
    return (x << r) | (x >> (32 - r));
}

__device__ __forceinline__ float gumbel_noise(unsigned i)
{
    const unsigned k0 = 0u, k1 = 42u, k2 = 0x1BD11BDAu ^ 0u ^ 42u;
    unsigned x0 = 0u;     // counts_hi
    unsigned x1 = i;      // counts_lo
#define TFR(r) { x0 += x1; x1 = rotl32(x1, r); x1 ^= x0; }
    x0 += k0; x1 += k1;
    TFR(13) TFR(15) TFR(26) TFR(6)
    x0 += k1; x1 += k2 + 1u;
    TFR(17) TFR(29) TFR(16) TFR(24)
    x0 += k2; x1 += k0 + 2u;
    TFR(13) TFR(15) TFR(26) TFR(6)
    x0 += k0; x1 += k1 + 3u;
    TFR(17) TFR(29) TFR(16) TFR(24)
    x0 += k1; x1 += k2 + 4u;
    TFR(13) TFR(15) TFR(26) TFR(6)
    x0 += k2; x1 += k0 + 5u;
#undef TFR
    unsigned bits = x0 ^ x1;
    float u = __uint_as_float((bits >> 9) | 0x3f800000u) - 1.0f;
    float uu = u > 0.f ? u : 1.175494350822288e-38f;   // max(tiny, u) — matches jax uniform
    return -logf(-logf(uu));
}

__global__ __launch_bounds__(256) void gumbel_argmax_kernel(
    const float* __restrict__ logits, float* __restrict__ out1)
{
    int row = blockIdx.x;
    unsigned base = (unsigned)row * VV;
    int t = threadIdx.x;
    float best = -3.4e38f;
    int bi = VV;
    for (int v = t; v < VV; v += 256) {
        float val = logits[base + v] + gumbel_noise(base + v);
        if (val > best) { best = val; bi = v; }   // keeps first occurrence
    }
    __shared__ float bv[256];
    __shared__ int bix[256];
    bv[t] = best; bix[t] = bi;
    __syncthreads();
    for (int off = 128; off; off >>= 1) {
        if (t < off) {
            float ov = bv[t + off]; int oi = bix[t + off];
            if (ov > bv[t] || (ov == bv[t] && oi < bix[t])) { bv[t] = ov; bix[t] = oi; }
        }
        __syncthreads();
    }
    int amax = bix[0];
    for (int v = t; v < VV; v += 256)
        out1[base + v] = (v == amax) ? 1.0f : 0.0f;
}

// ---------------------------------------------------------------- launch
extern "C" void kernel_launch(void* const* d_in, const int* in_sizes, int n_in,
                              void* d_out, int out_size, void* d_ws, size_t ws_size,
                              hipStream_t stream)
{
    const int*   ids   = (const int*)  d_in[0];
    const int*   cond  = (const int*)  d_in[1];
    const float* mask  = (const float*)d_in[2];
    // d_in[3] = inverse_temperature (==1, cancels in argmax) — unused
    const float* emb   = (const float*)d_in[4];
    const float* pos   = (const float*)d_in[5];
    const float* Wq    = (const float*)d_in[6];
    const float* bq    = (const float*)d_in[7];
    const float* Wk    = (const float*)d_in[8];
    const float* bk    = (const float*)d_in[9];
    const float* Wv    = (const float*)d_in[10];
    const float* bv    = (const float*)d_in[11];
    const float* Wo    = (const float*)d_in[12];
    const float* bo    = (const float*)d_in[13];
    const float* W1    = (const float*)d_in[14];
    const float* b1    = (const float*)d_in[15];
    const float* W2    = (const float*)d_in[16];
    const float* b2    = (const float*)d_in[17];
    const float* cn1g  = (const float*)d_in[18];
    const float* cn1b  = (const float*)d_in[19];
    const float* cn2g  = (const float*)d_in[20];
    const float* cn2b  = (const float*)d_in[21];
    const float* ng    = (const float*)d_in[22];
    const float* nb    = (const float*)d_in[23];
    const float* Wout  = (const float*)d_in[24];
    const float* bout  = (const float*)d_in[25];

    float* out0 = (float*)d_out;
    float* out1 = out0 + (size_t)NTOT;

    const size_t NX = (size_t)ROWS * DD;     // 1,048,576
    float* ws   = (float*)d_ws;
    float* x    = ws;
    float* xr   = x + NX;
    float* qb   = xr + NX;
    float* kb   = qb + NX;                   // NOTE: qb,kb contiguous -> split-K partials
    float* vb2  = kb + NX;
    float* ab   = vb2 + NX;
    float* h1   = ab + NX;                   // ROWS*FF = 4,194,304
    float* ctab = h1 + (size_t)ROWS * FF;
    float* stab = ctab + SS * 32;

    // chunk-attn scratch aliases h1 (free until the W1 gemm runs)
    float* stbuf = h1;
    float* zbuf  = h1 + (size_t)BB * HH * NCHUNK * 4096;

    embed_kernel<<<(ROWS * DD) / 256, 256, 0, stream>>>(ids, emb, pos, x);
    rope_table_kernel<<<(SS * 32) / 256, 256, 0, stream>>>(ctab, stab);

    for (int l = 0; l < LL; ++l) {
        const float* wq = Wq + (size_t)l * DD * DD;
        const float* wk = Wk + (size_t)l * DD * DD;
        const float* wv = Wv + (size_t)l * DD * DD;
        const float* wo = Wo + (size_t)l * DD * DD;
        const float* w1 = W1 + (size_t)l * DD * FF;
        const float* w2 = W2 + (size_t)l * FF * DD;

        // fused q,k,v projection: one launch, 768 blocks
        qkv_kernel<<<dim3(24, 32), 256, 0, stream>>>(
            x, wq, wk, wv, bq + l * DD, bk + l * DD, bv + l * DD, qb, kb, vb2);

        // chunked linear attention (rope+elu folded in, raw q/k inputs)
        chunk_state_kernel<<<BB * HH * NCHUNK, 256, 0, stream>>>(kb, vb2, ctab, stab, mask, stbuf, zbuf);
        chunk_prefix_kernel<<<BB * HH, 256, 0, stream>>>(stbuf, zbuf);
        chunk_scan_kernel<<<BB * HH * NCHUNK, 256, 0, stream>>>(qb, kb, vb2, ab, ctab, stab, mask, stbuf, zbuf);

        // o-projection: split-K=2 partials into qb/kb (free now), reduce in ln_fuse
        gemm_splitk_kernel<<<dim3(8, 32, 2), 256, 0, stream>>>(ab, wo, qb, ROWS, DD, DD);
        ln_fuse_kernel<<<ROWS, 256, 0, stream>>>(qb, kb, bo + l * DD, x,
                                                 cn1g + (size_t)l * 4 * DD, cn1b + (size_t)l * 4 * DD, cond);

        // MLP: W1 (gelu) 1024 blocks; W2 split-K=2 into qb/kb, reduce in ln_fuse
        gemm_kernel<<<dim3(FF / 64, ROWS / 64), 256, 0, stream>>>(x, w1, b1 + l * FF, nullptr, h1, ROWS, FF, DD, 1);
        gemm_splitk_kernel<<<dim3(8, 32, 2), 256, 0, stream>>>(h1, w2, qb, ROWS, DD, FF);
        ln_fuse_kernel<<<ROWS, 256, 0, stream>>>(qb, kb, b2 + l * DD, x,
                                                 cn2g + (size_t)l * 4 * DD, cn2b + (size_t)l * 4 * DD, cond);
    }

    ln_kernel<<<ROWS, 256, 0, stream>>>(x, xr, ng, nb, cond);

    dim3 gV128(VV / 128, ROWS / 128);
    gemm128_kernel<<<gV128, 256, 0, stream>>>(xr, Wout, bout, nullptr, out0, ROWS, VV, DD, 0);

    gumbel_argmax_kernel<<<ROWS, 256, 0, stream>>>(out0, out1);
}